// Round 12
// baseline (437.383 us; speedup 1.0000x reference)
//
#include <hip/hip_runtime.h>

#define DIMC 384
#define NHEADS 12
#define NTOK 144
#define TABLEN 529
#define BWIN 512
#define NWIN 16
#define CPBH 512

typedef unsigned short u16;
typedef unsigned int u32;
typedef __attribute__((ext_vector_type(8))) short short8;
typedef __attribute__((ext_vector_type(4))) float f32x4;

#define MFMA(a, b, c) __builtin_amdgcn_mfma_f32_16x16x32_bf16((a), (b), (c), 0, 0, 0)

__device__ __forceinline__ u16 f2bf(float f) {
  union { float f; u32 u; } v; v.f = f;
  u32 r = v.u + 0x7fffu + ((v.u >> 16) & 1u);
  return (u16)(r >> 16);
}
__device__ __forceinline__ u32 pk2(float a, float b) {
  return (u32)f2bf(a) | ((u32)f2bf(b) << 16);
}
__device__ __forceinline__ u32 cvtpk(float lo, float hi) {
  u32 r;
  asm("v_cvt_pk_bf16_f32 %0, %1, %2" : "=v"(r) : "v"(lo), "v"(hi));
  return r;
}

// ---------------- f32 -> bf16 bulk convert (weights only) ----------------
__global__ __launch_bounds__(256) void cvt_bf16(const float* __restrict__ in,
                                                u16* __restrict__ out, int n8) {
  int i = blockIdx.x * 256 + threadIdx.x;
  if (i >= n8) return;
  const float4* p = (const float4*)(in + (size_t)i * 8);
  float4 a = p[0], b = p[1];
  uint4 r;
  r.x = pk2(a.x, a.y); r.y = pk2(a.z, a.w);
  r.z = pk2(b.x, b.y); r.w = pk2(b.z, b.w);
  *(uint4*)(out + (size_t)i * 8) = r;
}

// ---------------- CPB-MLP table (529 x 12, sigmoid applied) + per-head scales ----------------
__global__ void cpb_kernel(const float* __restrict__ rct,
                           const float* __restrict__ w1,
                           const float* __restrict__ b1,
                           const float* __restrict__ w2,
                           const float* __restrict__ logit_scale,
                           float* __restrict__ bias_tab,
                           float* __restrict__ scalev) {
  int t = blockIdx.x * blockDim.x + threadIdx.x;
  if (t < NHEADS) scalev[t] = __expf(fminf(logit_scale[t], 4.60517018598809f));
  if (t >= TABLEN * NHEADS) return;
  int i = t / NHEADS, h = t % NHEADS;
  float c0 = rct[2 * i], c1 = rct[2 * i + 1];
  const float* w2h = w2 + (size_t)h * CPBH;
  float acc = 0.f;
  for (int k = 0; k < CPBH; ++k) {
    float hv = fmaxf(0.f, fmaf(c0, w1[2 * k], fmaf(c1, w1[2 * k + 1], b1[k])));
    acc = fmaf(hv, w2h[k], acc);
  }
  bias_tab[i * NHEADS + h] = 16.f / (1.f + __expf(-acc));
}

// ---------------- combined bias: cb[w][h][n][m] = rpb + mask (fp32) ----------------
__global__ __launch_bounds__(256) void cbias_kernel(const int* __restrict__ rpi,
                                                    const float* __restrict__ bias_tab,
                                                    const float* __restrict__ mask,
                                                    float* __restrict__ cb) {
  int e = blockIdx.x * 256 + threadIdx.x;
  if (e >= NWIN * NHEADS * NTOK * NTOK) return;
  int m = e % NTOK;
  int t = e / NTOK;
  int n = t % NTOK; t /= NTOK;
  int h = t % NHEADS;
  int w = t / NHEADS;
  cb[e] = bias_tab[rpi[n * NTOK + m] * NHEADS + h] + mask[(w * NTOK + n) * NTOK + m];
}

// ---------------- fused QKV-projection + cosine attention per (window b, head h) ----------------
// 576 threads = 9 waves; wave wv owns query rows [16wv, 16wv+16).
// R11-proven low-pressure decomposition (VGPR 36, zero spill).
// R12: phase-1 K=64 (12 barriers, 12 MFMA/wave/iter; R6-proven [64]-row 8-slot
// XOR swizzle = conflict-light) + x read as f32 with cvt fused into staging
// (R4-proven; deletes the 170MB x-convert pass).
__global__ __launch_bounds__(576) void attn_fused(
    const float* __restrict__ x, const u16* __restrict__ wb,
    const float* __restrict__ q_bias, const float* __restrict__ k_bias,
    const float* __restrict__ v_bias, const float* __restrict__ cb,
    const float* __restrict__ scalev, u16* __restrict__ ctx) {
  __shared__ u16 smem[22656];  // 45312 B -> 3 blocks/CU (LDS-wise)
  u16* qn = smem;               // [144][40] (phase 2+)
  u16* kn = smem + 5760;        // [144][40] (phase 2+)
  u16* vT = smem + 11520;       // [32][168] (phase 2+)
  u16* Pc = smem + 16896;       // [144][40] (phase 5, wave-private 16-row slices)
  u16* xs = smem;               // phase 1: [144][64] swizzled x tile (18432 B)
  u16* wsm = smem + 9216;       // phase 1: [96][64] swizzled W tile (12288 B)

  // w-grouped XCD decode: XCD x owns mask-windows {2x,2x+1}; cb set = 2.4MB < 4MB L2
  int bid = blockIdx.x;
  int xcd = bid & 7;
  int i = bid >> 3;
  int wsub = i / 384;
  int j = i - wsub * 384;
  int bI = j / NHEADS;
  int h = j - bI * NHEADS;
  int w = xcd * 2 + wsub;
  int b = bI * NWIN + w;

  int tid = threadIdx.x;
  int lane = tid & 63, wv = tid >> 6;   // wv 0..8
  int g = lane >> 4, c = lane & 15;
  int rbase = wv * 16;

  // ---- phase 1: QKV projection via MFMA, K chunked by 64, reg-prefetch 1 iter ahead ----
  f32x4 acc[6];
#pragma unroll
  for (int d = 0; d < 6; ++d) acc[d] = (f32x4){0.f, 0.f, 0.f, 0.f};

  // x tile: 144 rows x 8 blks = 1152 uint4; threads carry idx {tid, tid+576}
  // W tile: 96 rows x 8 blks = 768 uint4; idx {tid} + {576+tid : tid<192}
  int xr0 = tid >> 3, xk0 = tid & 7;            // idx0 = tid
  int xr1 = (tid + 576) >> 3, xk1 = tid & 7;    // idx1 = tid+576 (same low bits)
  bool hasW2 = tid < 192;
  int wr1 = (tid + 576) >> 3;                   // W idx1 rows 72..95
  int wrowg0 = (xr0 >> 5) * DIMC + h * 32 + (xr0 & 31);
  int wrowg1 = (wr1 >> 5) * DIMC + h * 32 + (wr1 & 31);
  const float* xrow0 = x + ((size_t)b * NTOK + xr0) * DIMC + xk0 * 8;
  const float* xrow1 = x + ((size_t)b * NTOK + xr1) * DIMC + xk1 * 8;
  // swizzled LDS write offsets (slot = blk ^ (row&7), rows 128B)
  int xo0 = xr0 * 64 + 8 * (xk0 ^ (xr0 & 7));
  int xo1 = xr1 * 64 + 8 * (xk1 ^ (xr1 & 7));
  int wo0 = xr0 * 64 + 8 * (xk0 ^ (xr0 & 7));  // same geometry for W rows 0..95 (xr0<96 when used? no: all threads stage W idx0 row=xr0? )
  // NOTE: W idx0 must use rows 0..71? 768 uint4, idx0 = tid covers 0..575 (rows 0..71), idx1 covers 576..767 (rows 72..95).
  int wr0 = tid >> 3;                 // rows 0..71 for W idx0
  int wk0 = tid & 7;
  int wrowg0b = (wr0 >> 5) * DIMC + h * 32 + (wr0 & 31);
  int woA = wr0 * 64 + 8 * (wk0 ^ (wr0 & 7));
  int woB = wr1 * 64 + 8 * (xk1 ^ (wr1 & 7));

  float4 pxa0, pxb0, pxa1, pxb1;
  uint4 pw0, pw1;
  {
    pxa0 = *(const float4*)xrow0; pxb0 = *(const float4*)(xrow0 + 4);
    pxa1 = *(const float4*)xrow1; pxb1 = *(const float4*)(xrow1 + 4);
    pw0 = *(const uint4*)(wb + (size_t)wrowg0b * DIMC + wk0 * 8);
    if (hasW2) pw1 = *(const uint4*)(wb + (size_t)wrowg1 * DIMC + xk1 * 8);
  }

  for (int t = 0; t < 6; ++t) {
    {
      uint4 v0 = (uint4){cvtpk(pxa0.x, pxa0.y), cvtpk(pxa0.z, pxa0.w),
                         cvtpk(pxb0.x, pxb0.y), cvtpk(pxb0.z, pxb0.w)};
      uint4 v1 = (uint4){cvtpk(pxa1.x, pxa1.y), cvtpk(pxa1.z, pxa1.w),
                         cvtpk(pxb1.x, pxb1.y), cvtpk(pxb1.z, pxb1.w)};
      *(uint4*)(xs + xo0) = v0;
      *(uint4*)(xs + xo1) = v1;
      *(uint4*)(wsm + woA) = pw0;
      if (hasW2) *(uint4*)(wsm + woB) = pw1;
    }
    __syncthreads();
    if (t < 5) {  // prefetch next K-tile (full MFMA block of latency coverage)
      int k0 = (t + 1) * 64;
      pxa0 = *(const float4*)(xrow0 + k0); pxb0 = *(const float4*)(xrow0 + k0 + 4);
      pxa1 = *(const float4*)(xrow1 + k0); pxb1 = *(const float4*)(xrow1 + k0 + 4);
      pw0 = *(const uint4*)(wb + (size_t)wrowg0b * DIMC + k0 + wk0 * 8);
      if (hasW2) pw1 = *(const uint4*)(wb + (size_t)wrowg1 * DIMC + k0 + xk1 * 8);
    }
    int arow = rbase + c;
#pragma unroll
    for (int kh = 0; kh < 2; ++kh) {
      short8 ax = *(const short8*)(xs + arow * 64 + 8 * ((g + 4 * kh) ^ (c & 7)));
#pragma unroll
      for (int ni = 0; ni < 6; ++ni) {
        int row = ni * 16 + c;
        short8 bw = *(const short8*)(wsm + row * 64 + 8 * ((g + 4 * kh) ^ (c & 7)));
        acc[ni] = MFMA(ax, bw, acc[ni]);
      }
    }
    __syncthreads();
  }

  // ---- phase 2: bias + cosine-normalize in-register, write qn/kn/vT ----
  float sch = scalev[h];
  float qb0 = q_bias[h * 32 + c], qb1 = q_bias[h * 32 + 16 + c];
  float kb0 = k_bias[h * 32 + c], kb1 = k_bias[h * 32 + 16 + c];
  float vb0 = v_bias[h * 32 + c], vb1 = v_bias[h * 32 + 16 + c];
#pragma unroll
  for (int r = 0; r < 4; ++r) {
    int row = rbase + g * 4 + r;
    float q0 = acc[0][r] + qb0, q1 = acc[1][r] + qb1;
    float ssq = q0 * q0 + q1 * q1;
    ssq += __shfl_xor(ssq, 1); ssq += __shfl_xor(ssq, 2);
    ssq += __shfl_xor(ssq, 4); ssq += __shfl_xor(ssq, 8);
    float siq = sch / sqrtf(ssq);
    qn[row * 40 + c] = f2bf(q0 * siq);
    qn[row * 40 + 16 + c] = f2bf(q1 * siq);
    float k0v = acc[2][r] + kb0, k1v = acc[3][r] + kb1;
    float ssk = k0v * k0v + k1v * k1v;
    ssk += __shfl_xor(ssk, 1); ssk += __shfl_xor(ssk, 2);
    ssk += __shfl_xor(ssk, 4); ssk += __shfl_xor(ssk, 8);
    float sik = 1.f / sqrtf(ssk);
    kn[row * 40 + c] = f2bf(k0v * sik);
    kn[row * 40 + 16 + c] = f2bf(k1v * sik);
    float v0 = acc[4][r] + vb0;
    float v1 = acc[5][r] + vb1;
    vT[c * 168 + row] = f2bf(v0);
    vT[(16 + c) * 168 + row] = f2bf(v1);
  }
  if (tid < 32) {  // zero the m-pad (144..167) so padded-K MFMA adds 0
    uint4 z4 = {0u, 0u, 0u, 0u};
    *(uint4*)(vT + tid * 168 + 144) = z4;
    *(uint4*)(vT + tid * 168 + 152) = z4;
    *(uint4*)(vT + tid * 168 + 160) = z4;
  }
  __syncthreads();

  // ---- phase 3: S = qn . kn^T (16x16x32 MFMA, K=d=32) ----
  short8 aq = *(const short8*)(qn + (rbase + c) * 40 + g * 8);
  f32x4 S[9];
#pragma unroll
  for (int mt = 0; mt < 9; ++mt) {
    short8 bk = *(const short8*)(kn + (mt * 16 + c) * 40 + g * 8);
    f32x4 z = (f32x4){0.f, 0.f, 0.f, 0.f};
    S[mt] = MFMA(aq, bk, z);
  }

  // ---- phase 4: + (rpb + mask), row softmax (folded 1/sum into P) ----
  const float* cbh = cb + (((size_t)w * NHEADS + h) * NTOK) * NTOK;
#pragma unroll
  for (int r = 0; r < 4; ++r) {
    int row = rbase + g * 4 + r;
    const float* crow = cbh + (size_t)row * NTOK + c;
    float sv[9];
    float mx = -1e30f;
#pragma unroll
    for (int mt = 0; mt < 9; ++mt) {
      float s = S[mt][r] + crow[mt * 16];
      sv[mt] = s;
      mx = fmaxf(mx, s);
    }
    mx = fmaxf(mx, __shfl_xor(mx, 1)); mx = fmaxf(mx, __shfl_xor(mx, 2));
    mx = fmaxf(mx, __shfl_xor(mx, 4)); mx = fmaxf(mx, __shfl_xor(mx, 8));
    float sum = 0.f;
#pragma unroll
    for (int mt = 0; mt < 9; ++mt) {
      float p = __expf(sv[mt] - mx);
      sv[mt] = p;
      sum += p;
    }
    sum += __shfl_xor(sum, 1); sum += __shfl_xor(sum, 2);
    sum += __shfl_xor(sum, 4); sum += __shfl_xor(sum, 8);
    float rinv = 1.f / sum;
#pragma unroll
    for (int mt = 0; mt < 9; ++mt) S[mt][r] = sv[mt] * rinv;
  }

  // ---- phase 5: PV, K(m) chunked by 32 via per-wave P bounce in LDS ----
  f32x4 po[2];
  po[0] = (f32x4){0.f, 0.f, 0.f, 0.f};
  po[1] = (f32x4){0.f, 0.f, 0.f, 0.f};
  for (int ck = 0; ck < 5; ++ck) {
#pragma unroll
    for (int mt2 = 0; mt2 < 2; ++mt2) {
      int MT = ck * 2 + mt2;
#pragma unroll
      for (int r = 0; r < 4; ++r) {
        int row = rbase + g * 4 + r;
        float p = (MT < 9) ? S[MT][r] : 0.f;
        Pc[row * 40 + mt2 * 16 + c] = f2bf(p);
      }
    }
    short8 pa = *(const short8*)(Pc + (rbase + c) * 40 + g * 8);
#pragma unroll
    for (int dt = 0; dt < 2; ++dt) {
      short8 vb = *(const short8*)(vT + (dt * 16 + c) * 168 + ck * 32 + g * 8);
      po[dt] = MFMA(pa, vb, po[dt]);
    }
  }

  // ---- epilogue: ctx[b*144+n][h*32+d] bf16 ----
#pragma unroll
  for (int dt = 0; dt < 2; ++dt)
#pragma unroll
    for (int r = 0; r < 4; ++r) {
      int n = rbase + g * 4 + r;
      ctx[((size_t)b * NTOK + n) * DIMC + h * 32 + dt * 16 + c] = f2bf(po[dt][r]);
    }
}

// ---------------- output projection: (73728 x 384) @ (384 x 384)^T + bias, bf16 MFMA ----------------
__global__ __launch_bounds__(256) void proj_gemm(const u16* __restrict__ ctx,
                                                 const u16* __restrict__ pwb,
                                                 const float* __restrict__ proj_b,
                                                 float* __restrict__ out) {
  __shared__ u16 As[128 * 64];
  __shared__ u16 Bs[128 * 64];
  int bid = blockIdx.x;
  int nblk = bid % 3, mblk = bid / 3;
  size_t gm0 = (size_t)mblk * 128;
  int gn0 = nblk * 128;
  int tid = threadIdx.x, lane = tid & 63, wid = tid >> 6;
  int wr = wid >> 1, wc = wid & 1, g = lane >> 4, c = lane & 15;
  f32x4 acc[4][4];
#pragma unroll
  for (int i = 0; i < 4; ++i)
#pragma unroll
    for (int j = 0; j < 4; ++j) acc[i][j] = (f32x4){0.f, 0.f, 0.f, 0.f};

  for (int t = 0; t < 6; ++t) {
    int k0 = t * 64;
#pragma unroll
    for (int p = 0; p < 4; ++p) {
      int row = p * 32 + (tid >> 3);
      int seg = (tid & 7) * 8;
      uint4 va = *(const uint4*)(ctx + (gm0 + row) * DIMC + k0 + seg);
      *(uint4*)(As + row * 64 + seg) = va;
      uint4 vb = *(const uint4*)(pwb + (size_t)(gn0 + row) * DIMC + k0 + seg);
      *(uint4*)(Bs + row * 64 + seg) = vb;
    }
    __syncthreads();
#pragma unroll
    for (int kk = 0; kk < 64; kk += 32) {
      short8 a[4], bfr[4];
#pragma unroll
      for (int mi = 0; mi < 4; ++mi)
        a[mi] = *(const short8*)(As + (wr * 64 + mi * 16 + c) * 64 + kk + g * 8);
#pragma unroll
      for (int ni = 0; ni < 4; ++ni)
        bfr[ni] = *(const short8*)(Bs + (wc * 64 + ni * 16 + c) * 64 + kk + g * 8);
#pragma unroll
      for (int mi = 0; mi < 4; ++mi)
#pragma unroll
        for (int ni = 0; ni < 4; ++ni)
          acc[mi][ni] = MFMA(a[mi], bfr[ni], acc[mi][ni]);
    }
    __syncthreads();
  }
#pragma unroll
  for (int mi = 0; mi < 4; ++mi)
#pragma unroll
    for (int ni = 0; ni < 4; ++ni) {
      int gcol = gn0 + wc * 64 + ni * 16 + c;
      float bv = proj_b[gcol];
#pragma unroll
      for (int r = 0; r < 4; ++r) {
        size_t grow = gm0 + wr * 64 + mi * 16 + g * 4 + r;
        out[grow * DIMC + gcol] = acc[mi][ni][r] + bv;
      }
    }
}

extern "C" void kernel_launch(void* const* d_in, const int* in_sizes, int n_in,
                              void* d_out, int out_size, void* d_ws, size_t ws_size,
                              hipStream_t stream) {
  const float* x = (const float*)d_in[0];
  const float* rct = (const float*)d_in[1];
  const int* rpi = (const int*)d_in[2];
  const float* mask = (const float*)d_in[3];
  const float* qkv_w = (const float*)d_in[4];
  const float* q_bias = (const float*)d_in[5];
  const float* k_bias = (const float*)d_in[6];
  const float* v_bias = (const float*)d_in[7];
  const float* logit_scale = (const float*)d_in[8];
  const float* cpb_w1 = (const float*)d_in[9];
  const float* cpb_b1 = (const float*)d_in[10];
  const float* cpb_w2 = (const float*)d_in[11];
  const float* proj_w = (const float*)d_in[12];
  const float* proj_b = (const float*)d_in[13];
  float* out = (float*)d_out;

  char* ws = (char*)d_ws;
  size_t off = 0;
  auto alloc = [&](size_t bytes) {
    void* p = ws + off;
    off = (off + bytes + 255) & ~(size_t)255;
    return p;
  };
  const size_t NX = (size_t)BWIN * NTOK * DIMC;  // 28311552
  u16* wqb = (u16*)alloc((size_t)3 * DIMC * DIMC * 2);
  u16* pwb = (u16*)alloc((size_t)DIMC * DIMC * 2);
  u16* ctx = (u16*)alloc(NX * 2);
  float* cbv = (float*)alloc((size_t)NWIN * NHEADS * NTOK * NTOK * 4);
  float* bias_tab = (float*)alloc((size_t)TABLEN * NHEADS * 4);
  float* scalev = (float*)alloc(64 * 4);

  cvt_bf16<<<(3 * DIMC * DIMC / 8 + 255) / 256, 256, 0, stream>>>(qkv_w, wqb, 3 * DIMC * DIMC / 8);
  cvt_bf16<<<(DIMC * DIMC / 8 + 255) / 256, 256, 0, stream>>>(proj_w, pwb, DIMC * DIMC / 8);
  cpb_kernel<<<(TABLEN * NHEADS + 255) / 256, 256, 0, stream>>>(
      rct, cpb_w1, cpb_b1, cpb_w2, logit_scale, bias_tab, scalev);
  cbias_kernel<<<(NWIN * NHEADS * NTOK * NTOK + 255) / 256, 256, 0, stream>>>(
      rpi, bias_tab, mask, cbv);
  attn_fused<<<BWIN * NHEADS, 576, 0, stream>>>(
      x, wqb, q_bias, k_bias, v_bias, cbv, scalev, ctx);
  proj_gemm<<<(BWIN * NTOK / 128) * 3, 256, 0, stream>>>(ctx, pwb, proj_b, out);
}

// Round 13
// 350.180 us; speedup vs baseline: 1.2490x; 1.2490x over previous
//
#include <hip/hip_runtime.h>

#define DIMC 384
#define NHEADS 12
#define NTOK 144
#define TABLEN 529
#define BWIN 512
#define NWIN 16
#define CPBH 512

typedef unsigned short u16;
typedef unsigned int u32;
typedef __attribute__((ext_vector_type(8))) short short8;
typedef __attribute__((ext_vector_type(4))) float f32x4;

#define MFMA(a, b, c) __builtin_amdgcn_mfma_f32_16x16x32_bf16((a), (b), (c), 0, 0, 0)

__device__ __forceinline__ u16 f2bf(float f) {
  union { float f; u32 u; } v; v.f = f;
  u32 r = v.u + 0x7fffu + ((v.u >> 16) & 1u);
  return (u16)(r >> 16);
}
__device__ __forceinline__ u32 pk2(float a, float b) {
  return (u32)f2bf(a) | ((u32)f2bf(b) << 16);
}

// ---------------- f32 -> bf16 bulk convert ----------------
__global__ __launch_bounds__(256) void cvt_bf16(const float* __restrict__ in,
                                                u16* __restrict__ out, int n8) {
  int i = blockIdx.x * 256 + threadIdx.x;
  if (i >= n8) return;
  const float4* p = (const float4*)(in + (size_t)i * 8);
  float4 a = p[0], b = p[1];
  uint4 r;
  r.x = pk2(a.x, a.y); r.y = pk2(a.z, a.w);
  r.z = pk2(b.x, b.y); r.w = pk2(b.z, b.w);
  *(uint4*)(out + (size_t)i * 8) = r;
}

// ---------------- CPB-MLP table (529 x 12, sigmoid applied) + per-head scales ----------------
__global__ void cpb_kernel(const float* __restrict__ rct,
                           const float* __restrict__ w1,
                           const float* __restrict__ b1,
                           const float* __restrict__ w2,
                           const float* __restrict__ logit_scale,
                           float* __restrict__ bias_tab,
                           float* __restrict__ scalev) {
  int t = blockIdx.x * blockDim.x + threadIdx.x;
  if (t < NHEADS) scalev[t] = __expf(fminf(logit_scale[t], 4.60517018598809f));
  if (t >= TABLEN * NHEADS) return;
  int i = t / NHEADS, h = t % NHEADS;
  float c0 = rct[2 * i], c1 = rct[2 * i + 1];
  const float* w2h = w2 + (size_t)h * CPBH;
  float acc = 0.f;
  for (int k = 0; k < CPBH; ++k) {
    float hv = fmaxf(0.f, fmaf(c0, w1[2 * k], fmaf(c1, w1[2 * k + 1], b1[k])));
    acc = fmaf(hv, w2h[k], acc);
  }
  bias_tab[i * NHEADS + h] = 16.f / (1.f + __expf(-acc));
}

// ---------------- combined bias: cb[w][h][n][m] = rpb + mask (fp32) ----------------
__global__ __launch_bounds__(256) void cbias_kernel(const int* __restrict__ rpi,
                                                    const float* __restrict__ bias_tab,
                                                    const float* __restrict__ mask,
                                                    float* __restrict__ cb) {
  int e = blockIdx.x * 256 + threadIdx.x;
  if (e >= NWIN * NHEADS * NTOK * NTOK) return;
  int m = e % NTOK;
  int t = e / NTOK;
  int n = t % NTOK; t /= NTOK;
  int h = t % NHEADS;
  int w = t / NHEADS;
  cb[e] = bias_tab[rpi[n * NTOK + m] * NHEADS + h] + mask[(w * NTOK + n) * NTOK + m];
}

// ---------------- fused QKV-projection + cosine attention per (window b, head h) ----------------
// 576 threads = 9 waves; wave wv owns query rows [16wv, 16wv+16).
// R11-proven decomposition (VGPR 36, zero spill). R13 change (ONLY phase-1 geometry):
// staging rows are 128B ([64] u16) with the two consecutive K=32 tiles double-buffered
// in row HALVES (content chunk b4+4*(t&1), physical slot chunk^(row&7)).
//  - 8-slot XOR swizzle = R12-measured conflict fix (2.5e7 -> ~6e6)
//  - half-buffering removes the read->write barrier: 1 barrier/iter (13 total vs 24).
//    Safety: store(t+1) goes to the other half; any wave's store(t+2) (same half as t)
//    is ordered behind all reads of tile t via the single barrier + program order.
__global__ __launch_bounds__(576) void attn_fused(
    const u16* __restrict__ xb, const u16* __restrict__ wb,
    const float* __restrict__ q_bias, const float* __restrict__ k_bias,
    const float* __restrict__ v_bias, const float* __restrict__ cb,
    const float* __restrict__ scalev, u16* __restrict__ ctx) {
  __shared__ u16 smem[22656];  // 45312 B -> 3 blocks/CU (LDS-wise)
  u16* qn = smem;               // [144][40] (phase 2+)
  u16* kn = smem + 5760;        // [144][40] (phase 2+)
  u16* vT = smem + 11520;       // [32][168] (phase 2+)
  u16* Pc = smem + 16896;       // [144][40] (phase 5, wave-private 16-row slices)
  u16* xs = smem;               // phase 1: [144][64] half-buffered x rows (18432 B)
  u16* wsm = smem + 9216;       // phase 1: [96][64] half-buffered W rows (12288 B)

  // w-grouped XCD decode: XCD x owns mask-windows {2x,2x+1}; cb set = 2.4MB < 4MB L2
  int bid = blockIdx.x;
  int xcd = bid & 7;
  int i = bid >> 3;
  int wsub = i / 384;
  int j = i - wsub * 384;
  int bI = j / NHEADS;
  int h = j - bI * NHEADS;
  int w = xcd * 2 + wsub;
  int b = bI * NWIN + w;

  int tid = threadIdx.x;
  int lane = tid & 63, wv = tid >> 6;   // wv 0..8
  int g = lane >> 4, c = lane & 15;
  int rbase = wv * 16;

  // ---- phase 1: QKV projection via MFMA, K chunked by 32, reg-prefetch 1 iter ahead ----
  f32x4 acc[6];
#pragma unroll
  for (int d = 0; d < 6; ++d) acc[d] = (f32x4){0.f, 0.f, 0.f, 0.f};

  int r4 = tid >> 2, b4 = tid & 3;  // x: row r4 (0..143), 16B content chunk b4
  bool hasW = tid < 384;            // W: row r4 (0..95) on threads 0..383
  int wrow = (r4 >> 5) * DIMC + h * 32 + (r4 & 31);
  // physical slot for content chunk (b4 + 4*parity), XORed with row&7
  int xwo0 = r4 * 64 + 8 * (b4 ^ (r4 & 7));        // parity 0 (chunks 0..3)
  int xwo1 = r4 * 64 + 8 * ((b4 + 4) ^ (r4 & 7));  // parity 1 (chunks 4..7)

  uint4 px, pw;
  px = *(const uint4*)(xb + ((size_t)b * NTOK + r4) * DIMC + b4 * 8);
  if (hasW) pw = *(const uint4*)(wb + (size_t)wrow * DIMC + b4 * 8);

  for (int t = 0; t < 12; ++t) {
    int xwo = (t & 1) ? xwo1 : xwo0;
    *(uint4*)(xs + xwo) = px;
    if (hasW) *(uint4*)(wsm + xwo) = pw;
    __syncthreads();  // tile t resident (single barrier per iter)
    if (t < 11) {     // prefetch next tile (one full MFMA block of coverage)
      int k0 = (t + 1) * 32;
      px = *(const uint4*)(xb + ((size_t)b * NTOK + r4) * DIMC + k0 + b4 * 8);
      if (hasW) pw = *(const uint4*)(wb + (size_t)wrow * DIMC + k0 + b4 * 8);
    }
    int par4 = (t & 1) * 4;
    int arow = rbase + c;
    short8 ax = *(const short8*)(xs + arow * 64 + 8 * ((g + par4) ^ (arow & 7)));
#pragma unroll
    for (int ni = 0; ni < 6; ++ni) {
      int row = ni * 16 + c;
      short8 bw = *(const short8*)(wsm + row * 64 + 8 * ((g + par4) ^ (row & 7)));
      acc[ni] = MFMA(ax, bw, acc[ni]);
    }
    // no trailing barrier: next iter writes the other half
  }
  __syncthreads();  // all phase-1 reads done; xs/wsm region may be overwritten

  // ---- phase 2: bias + cosine-normalize in-register, write qn/kn/vT ----
  float sch = scalev[h];
  float qb0 = q_bias[h * 32 + c], qb1 = q_bias[h * 32 + 16 + c];
  float kb0 = k_bias[h * 32 + c], kb1 = k_bias[h * 32 + 16 + c];
  float vb0 = v_bias[h * 32 + c], vb1 = v_bias[h * 32 + 16 + c];
#pragma unroll
  for (int r = 0; r < 4; ++r) {
    int row = rbase + g * 4 + r;
    float q0 = acc[0][r] + qb0, q1 = acc[1][r] + qb1;
    float ssq = q0 * q0 + q1 * q1;
    ssq += __shfl_xor(ssq, 1); ssq += __shfl_xor(ssq, 2);
    ssq += __shfl_xor(ssq, 4); ssq += __shfl_xor(ssq, 8);
    float siq = sch / sqrtf(ssq);
    qn[row * 40 + c] = f2bf(q0 * siq);
    qn[row * 40 + 16 + c] = f2bf(q1 * siq);
    float k0v = acc[2][r] + kb0, k1v = acc[3][r] + kb1;
    float ssk = k0v * k0v + k1v * k1v;
    ssk += __shfl_xor(ssk, 1); ssk += __shfl_xor(ssk, 2);
    ssk += __shfl_xor(ssk, 4); ssk += __shfl_xor(ssk, 8);
    float sik = 1.f / sqrtf(ssk);
    kn[row * 40 + c] = f2bf(k0v * sik);
    kn[row * 40 + 16 + c] = f2bf(k1v * sik);
    float v0 = acc[4][r] + vb0;
    float v1 = acc[5][r] + vb1;
    vT[c * 168 + row] = f2bf(v0);
    vT[(16 + c) * 168 + row] = f2bf(v1);
  }
  if (tid < 32) {  // zero the m-pad (144..167) so padded-K MFMA adds 0
    uint4 z4 = {0u, 0u, 0u, 0u};
    *(uint4*)(vT + tid * 168 + 144) = z4;
    *(uint4*)(vT + tid * 168 + 152) = z4;
    *(uint4*)(vT + tid * 168 + 160) = z4;
  }
  __syncthreads();

  // ---- phase 3: S = qn . kn^T (16x16x32 MFMA, K=d=32) ----
  short8 aq = *(const short8*)(qn + (rbase + c) * 40 + g * 8);
  f32x4 S[9];
#pragma unroll
  for (int mt = 0; mt < 9; ++mt) {
    short8 bk = *(const short8*)(kn + (mt * 16 + c) * 40 + g * 8);
    f32x4 z = (f32x4){0.f, 0.f, 0.f, 0.f};
    S[mt] = MFMA(aq, bk, z);
  }

  // ---- phase 4: + (rpb + mask), row softmax (folded 1/sum into P) ----
  const float* cbh = cb + (((size_t)w * NHEADS + h) * NTOK) * NTOK;
#pragma unroll
  for (int r = 0; r < 4; ++r) {
    int row = rbase + g * 4 + r;
    const float* crow = cbh + (size_t)row * NTOK + c;
    float sv[9];
    float mx = -1e30f;
#pragma unroll
    for (int mt = 0; mt < 9; ++mt) {
      float s = S[mt][r] + crow[mt * 16];
      sv[mt] = s;
      mx = fmaxf(mx, s);
    }
    mx = fmaxf(mx, __shfl_xor(mx, 1)); mx = fmaxf(mx, __shfl_xor(mx, 2));
    mx = fmaxf(mx, __shfl_xor(mx, 4)); mx = fmaxf(mx, __shfl_xor(mx, 8));
    float sum = 0.f;
#pragma unroll
    for (int mt = 0; mt < 9; ++mt) {
      float p = __expf(sv[mt] - mx);
      sv[mt] = p;
      sum += p;
    }
    sum += __shfl_xor(sum, 1); sum += __shfl_xor(sum, 2);
    sum += __shfl_xor(sum, 4); sum += __shfl_xor(sum, 8);
    float rinv = 1.f / sum;
#pragma unroll
    for (int mt = 0; mt < 9; ++mt) S[mt][r] = sv[mt] * rinv;
  }

  // ---- phase 5: PV, K(m) chunked by 32 via per-wave P bounce in LDS ----
  f32x4 po[2];
  po[0] = (f32x4){0.f, 0.f, 0.f, 0.f};
  po[1] = (f32x4){0.f, 0.f, 0.f, 0.f};
  for (int ck = 0; ck < 5; ++ck) {
#pragma unroll
    for (int mt2 = 0; mt2 < 2; ++mt2) {
      int MT = ck * 2 + mt2;
#pragma unroll
      for (int r = 0; r < 4; ++r) {
        int row = rbase + g * 4 + r;
        float p = (MT < 9) ? S[MT][r] : 0.f;
        Pc[row * 40 + mt2 * 16 + c] = f2bf(p);
      }
    }
    short8 pa = *(const short8*)(Pc + (rbase + c) * 40 + g * 8);
#pragma unroll
    for (int dt = 0; dt < 2; ++dt) {
      short8 vb = *(const short8*)(vT + (dt * 16 + c) * 168 + ck * 32 + g * 8);
      po[dt] = MFMA(pa, vb, po[dt]);
    }
  }

  // ---- epilogue: ctx[b*144+n][h*32+d] bf16 ----
#pragma unroll
  for (int dt = 0; dt < 2; ++dt)
#pragma unroll
    for (int r = 0; r < 4; ++r) {
      int n = rbase + g * 4 + r;
      ctx[((size_t)b * NTOK + n) * DIMC + h * 32 + dt * 16 + c] = f2bf(po[dt][r]);
    }
}

// ---------------- output projection: (73728 x 384) @ (384 x 384)^T + bias, bf16 MFMA ----------------
__global__ __launch_bounds__(256) void proj_gemm(const u16* __restrict__ ctx,
                                                 const u16* __restrict__ pwb,
                                                 const float* __restrict__ proj_b,
                                                 float* __restrict__ out) {
  __shared__ u16 As[128 * 64];
  __shared__ u16 Bs[128 * 64];
  int bid = blockIdx.x;
  int nblk = bid % 3, mblk = bid / 3;
  size_t gm0 = (size_t)mblk * 128;
  int gn0 = nblk * 128;
  int tid = threadIdx.x, lane = tid & 63, wid = tid >> 6;
  int wr = wid >> 1, wc = wid & 1, g = lane >> 4, c = lane & 15;
  f32x4 acc[4][4];
#pragma unroll
  for (int i = 0; i < 4; ++i)
#pragma unroll
    for (int j = 0; j < 4; ++j) acc[i][j] = (f32x4){0.f, 0.f, 0.f, 0.f};

  for (int t = 0; t < 6; ++t) {
    int k0 = t * 64;
#pragma unroll
    for (int p = 0; p < 4; ++p) {
      int row = p * 32 + (tid >> 3);
      int seg = (tid & 7) * 8;
      uint4 va = *(const uint4*)(ctx + (gm0 + row) * DIMC + k0 + seg);
      *(uint4*)(As + row * 64 + seg) = va;
      uint4 vb = *(const uint4*)(pwb + (size_t)(gn0 + row) * DIMC + k0 + seg);
      *(uint4*)(Bs + row * 64 + seg) = vb;
    }
    __syncthreads();
#pragma unroll
    for (int kk = 0; kk < 64; kk += 32) {
      short8 a[4], bfr[4];
#pragma unroll
      for (int mi = 0; mi < 4; ++mi)
        a[mi] = *(const short8*)(As + (wr * 64 + mi * 16 + c) * 64 + kk + g * 8);
#pragma unroll
      for (int ni = 0; ni < 4; ++ni)
        bfr[ni] = *(const short8*)(Bs + (wc * 64 + ni * 16 + c) * 64 + kk + g * 8);
#pragma unroll
      for (int mi = 0; mi < 4; ++mi)
#pragma unroll
        for (int ni = 0; ni < 4; ++ni)
          acc[mi][ni] = MFMA(a[mi], bfr[ni], acc[mi][ni]);
    }
    __syncthreads();
  }
#pragma unroll
  for (int mi = 0; mi < 4; ++mi)
#pragma unroll
    for (int ni = 0; ni < 4; ++ni) {
      int gcol = gn0 + wc * 64 + ni * 16 + c;
      float bv = proj_b[gcol];
#pragma unroll
      for (int r = 0; r < 4; ++r) {
        size_t grow = gm0 + wr * 64 + mi * 16 + g * 4 + r;
        out[grow * DIMC + gcol] = acc[mi][ni][r] + bv;
      }
    }
}

extern "C" void kernel_launch(void* const* d_in, const int* in_sizes, int n_in,
                              void* d_out, int out_size, void* d_ws, size_t ws_size,
                              hipStream_t stream) {
  const float* x = (const float*)d_in[0];
  const float* rct = (const float*)d_in[1];
  const int* rpi = (const int*)d_in[2];
  const float* mask = (const float*)d_in[3];
  const float* qkv_w = (const float*)d_in[4];
  const float* q_bias = (const float*)d_in[5];
  const float* k_bias = (const float*)d_in[6];
  const float* v_bias = (const float*)d_in[7];
  const float* logit_scale = (const float*)d_in[8];
  const float* cpb_w1 = (const float*)d_in[9];
  const float* cpb_b1 = (const float*)d_in[10];
  const float* cpb_w2 = (const float*)d_in[11];
  const float* proj_w = (const float*)d_in[12];
  const float* proj_b = (const float*)d_in[13];
  float* out = (float*)d_out;

  char* ws = (char*)d_ws;
  size_t off = 0;
  auto alloc = [&](size_t bytes) {
    void* p = ws + off;
    off = (off + bytes + 255) & ~(size_t)255;
    return p;
  };
  const size_t NX = (size_t)BWIN * NTOK * DIMC;  // 28311552
  u16* xb = (u16*)alloc(NX * 2);
  u16* wqb = (u16*)alloc((size_t)3 * DIMC * DIMC * 2);
  u16* pwb = (u16*)alloc((size_t)DIMC * DIMC * 2);
  u16* ctx = (u16*)alloc(NX * 2);
  float* cbv = (float*)alloc((size_t)NWIN * NHEADS * NTOK * NTOK * 4);
  float* bias_tab = (float*)alloc((size_t)TABLEN * NHEADS * 4);
  float* scalev = (float*)alloc(64 * 4);

  cvt_bf16<<<(int)(NX / 8 + 255) / 256, 256, 0, stream>>>(x, xb, (int)(NX / 8));
  cvt_bf16<<<(3 * DIMC * DIMC / 8 + 255) / 256, 256, 0, stream>>>(qkv_w, wqb, 3 * DIMC * DIMC / 8);
  cvt_bf16<<<(DIMC * DIMC / 8 + 255) / 256, 256, 0, stream>>>(proj_w, pwb, DIMC * DIMC / 8);
  cpb_kernel<<<(TABLEN * NHEADS + 255) / 256, 256, 0, stream>>>(
      rct, cpb_w1, cpb_b1, cpb_w2, logit_scale, bias_tab, scalev);
  cbias_kernel<<<(NWIN * NHEADS * NTOK * NTOK + 255) / 256, 256, 0, stream>>>(
      rpi, bias_tab, mask, cbv);
  attn_fused<<<BWIN * NHEADS, 576, 0, stream>>>(
      xb, wqb, q_bias, k_bias, v_bias, cbv, scalev, ctx);
  proj_gemm<<<(BWIN * NTOK / 128) * 3, 256, 0, stream>>>(ctx, pwb, proj_b, out);
}